// Round 9
// baseline (987.517 us; speedup 1.0000x reference)
//
#include <hip/hip_runtime.h>
#include <math.h>

#define NN 50000
#define NE 800000
#define FF 768
#define HH 256

typedef __attribute__((ext_vector_type(8))) short short8;
typedef __attribute__((ext_vector_type(4))) float f32x4;

__device__ inline unsigned short f2bf(float f) {
  unsigned u = __float_as_uint(f);
  u = u + 0x7fffu + ((u >> 16) & 1u);
  return (unsigned short)(u >> 16);
}
__device__ inline float bf2f(unsigned short b) {
  return __uint_as_float(((unsigned)b) << 16);
}

// async global->LDS, 16B per lane. Dest is wave-uniform base + lane*16 (HW).
__device__ __forceinline__ void ldsload16(const unsigned short* g, unsigned short* l) {
  __builtin_amdgcn_global_load_lds(
      (const __attribute__((address_space(1))) void*)g,
      (__attribute__((address_space(3))) void*)l, 16, 0, 0);
}

// ---------------- CSR build ----------------
__global__ void k_count(const int* __restrict__ dstv, int* __restrict__ deg) {
  int e = blockIdx.x * 256 + threadIdx.x;
  if (e < NE) atomicAdd(&deg[dstv[e]], 1);
}

// single-block thread-coarsened scan: 1024 threads x 49 elems
__global__ void k_scan(const int* __restrict__ deg, int* __restrict__ rowptr) {
  const int CH = 49;  // 1024*49 = 50176 >= NN
  int tid = threadIdx.x;
  int lane = tid & 63, w = tid >> 6;
  int base = tid * CH;
  int sum = 0;
  for (int i = 0; i < CH; i++) {
    int idx = base + i;
    if (idx < NN) sum += deg[idx];
  }
  int incl = sum;
  for (int off = 1; off < 64; off <<= 1) {
    int tv = __shfl_up(incl, off, 64);
    if (lane >= off) incl += tv;
  }
  __shared__ int ws[16];
  if (lane == 63) ws[w] = incl;
  __syncthreads();
  if (tid == 0) {
    int c = 0;
    for (int i = 0; i < 16; i++) { int tv = ws[i]; ws[i] = c; c += tv; }
  }
  __syncthreads();
  int run = ws[w] + (incl - sum);
  if (tid == 0) rowptr[0] = 0;
  for (int i = 0; i < CH; i++) {
    int idx = base + i;
    if (idx < NN) { run += deg[idx]; rowptr[idx + 1] = run; }
  }
}

__global__ void k_scatter(const int* __restrict__ srcv, const int* __restrict__ dstv,
                          int* __restrict__ cursor, int* __restrict__ csr_src) {
  int e = blockIdx.x * 256 + threadIdx.x;
  if (e < NE) {
    int d = dstv[e];
    int pos = atomicAdd(&cursor[d], 1);
    csr_src[pos] = srcv[e];
  }
}

// ------------- aggregation (bf16 gather): mb = bf16((1+eps)*hb + sum hb[src]) -------------
// 4-wide edge batching: break the index->gather dependent chain (4 gathers in flight).
__global__ void k_agg(const unsigned short* __restrict__ hb, const int* __restrict__ rowptr,
                      const int* __restrict__ csr_src, const float* __restrict__ eps,
                      int layer, unsigned short* __restrict__ mb) {
  int node = (blockIdx.x * blockDim.x + threadIdx.x) >> 6;
  int lane = threadIdx.x & 63;
  if (node >= NN) return;
  int beg = rowptr[node], end = rowptr[node + 1];
  const ushort4* hv = (const ushort4*)hb;
  float ax = 0.f, ay = 0.f, az = 0.f, aw = 0.f;
  int e = beg;
  for (; e + 3 < end; e += 4) {
    int s0 = csr_src[e], s1 = csr_src[e + 1], s2 = csr_src[e + 2], s3 = csr_src[e + 3];
    ushort4 v0 = hv[(size_t)s0 * 64 + lane];
    ushort4 v1 = hv[(size_t)s1 * 64 + lane];
    ushort4 v2 = hv[(size_t)s2 * 64 + lane];
    ushort4 v3 = hv[(size_t)s3 * 64 + lane];
    ax += bf2f(v0.x) + bf2f(v1.x) + bf2f(v2.x) + bf2f(v3.x);
    ay += bf2f(v0.y) + bf2f(v1.y) + bf2f(v2.y) + bf2f(v3.y);
    az += bf2f(v0.z) + bf2f(v1.z) + bf2f(v2.z) + bf2f(v3.z);
    aw += bf2f(v0.w) + bf2f(v1.w) + bf2f(v2.w) + bf2f(v3.w);
  }
  for (; e < end; ++e) {
    int s = csr_src[e];
    ushort4 v = hv[(size_t)s * 64 + lane];
    ax += bf2f(v.x); ay += bf2f(v.y); az += bf2f(v.z); aw += bf2f(v.w);
  }
  float ep = 1.0f + eps[layer];
  ushort4 h0 = hv[(size_t)node * 64 + lane];
  ax += ep * bf2f(h0.x); ay += ep * bf2f(h0.y);
  az += ep * bf2f(h0.z); aw += ep * bf2f(h0.w);
  ushort4 o;
  o.x = f2bf(ax); o.y = f2bf(ay); o.z = f2bf(az); o.w = f2bf(aw);
  *(ushort4*)&mb[(size_t)node * 256 + lane * 4] = o;
}

// ------------- transpose + cast: dst[c][r] = bf16(src[r][c]), src is R x C, batched over z -------------
__global__ void k_tcast(const float* __restrict__ src0, unsigned short* __restrict__ dst0,
                        int R, int C) {
  const float* src = src0 + (size_t)blockIdx.z * R * C;
  unsigned short* dst = dst0 + (size_t)blockIdx.z * R * C;
  __shared__ float tile[32][33];
  int bx = blockIdx.x * 32, by = blockIdx.y * 32;
  int tx = threadIdx.x & 31, ty = threadIdx.x >> 5;  // 32 x 8
  for (int i = 0; i < 32; i += 8) {
    int r = by + ty + i, c = bx + tx;
    tile[ty + i][tx] = (r < R && c < C) ? src[(size_t)r * C + c] : 0.f;
  }
  __syncthreads();
  for (int i = 0; i < 32; i += 8) {
    int c = bx + ty + i, r = by + tx;
    if (c < C && r < R) dst[(size_t)c * R + r] = f2bf(tile[tx][ty + i]);
  }
}

// ---------------- input projection GEMM: K=768, fp32 A cast in staging (R6 path) ----------------
__global__ __launch_bounds__(256) void k_mmff(
    const float* __restrict__ x, const unsigned short* __restrict__ Bt,
    const float* __restrict__ bias, float* __restrict__ outf,
    unsigned short* __restrict__ outb) {
  __shared__ unsigned short As[64 * 32];   // 4 KB, linear (swizzled slots)
  __shared__ unsigned short Bs[256 * 32];  // 16 KB, linear (swizzled slots)
  int t = threadIdx.x, lane = t & 63, wave = t >> 6;
  int row0 = blockIdx.x * 64;
  f32x4 acc[4][4];
#pragma unroll
  for (int i = 0; i < 4; i++)
#pragma unroll
    for (int j = 0; j < 4; j++) acc[i][j] = (f32x4)(0.f);
  int m16 = lane & 15, kq = lane >> 4;
  int arow = t >> 2, a2 = t & 3;
  int asl = a2 ^ (arow & 3);
  int agr = row0 + arow; if (agr >= NN) agr = NN - 1;
  int brow_[4], bsl_[4];
#pragma unroll
  for (int j = 0; j < 4; j++) {
    int s = j * 256 + t;
    brow_[j] = s >> 2;
    bsl_[j] = (s & 3) ^ (brow_[j] & 3);
  }
  for (int k0 = 0; k0 < FF; k0 += 32) {
    {
      const float* Af = x + (size_t)agr * FF + k0 + asl * 8;
      float4 f0 = *(const float4*)Af;
      float4 f1 = *(const float4*)(Af + 4);
      short8 v;
      v[0] = (short)f2bf(f0.x); v[1] = (short)f2bf(f0.y);
      v[2] = (short)f2bf(f0.z); v[3] = (short)f2bf(f0.w);
      v[4] = (short)f2bf(f1.x); v[5] = (short)f2bf(f1.y);
      v[6] = (short)f2bf(f1.z); v[7] = (short)f2bf(f1.w);
      *(short8*)&As[arow * 32 + a2 * 8] = v;
    }
#pragma unroll
    for (int j = 0; j < 4; j++)
      ldsload16(&Bt[(size_t)brow_[j] * FF + k0 + bsl_[j] * 8],
                &Bs[(j * 256 + wave * 64) * 8]);
    __syncthreads();
    short8 a[4], b[4];
#pragma unroll
    for (int rt = 0; rt < 4; rt++) {
      int row = rt * 16 + m16;
      a[rt] = *(const short8*)&As[row * 32 + ((kq ^ (row & 3)) * 8)];
    }
#pragma unroll
    for (int ct = 0; ct < 4; ct++) {
      int row = wave * 64 + ct * 16 + m16;
      b[ct] = *(const short8*)&Bs[row * 32 + ((kq ^ (row & 3)) * 8)];
    }
#pragma unroll
    for (int rt = 0; rt < 4; rt++)
#pragma unroll
      for (int ct = 0; ct < 4; ct++)
        acc[rt][ct] = __builtin_amdgcn_mfma_f32_16x16x32_bf16(a[rt], b[ct], acc[rt][ct], 0, 0, 0);
    __syncthreads();
  }
  int colbase = wave * 64 + m16;
  float bv[4];
#pragma unroll
  for (int ct = 0; ct < 4; ct++) bv[ct] = bias[colbase + ct * 16];
#pragma unroll
  for (int rt = 0; rt < 4; rt++)
#pragma unroll
    for (int reg = 0; reg < 4; reg++) {
      int r = row0 + rt * 16 + kq * 4 + reg;
      if (r < NN) {
#pragma unroll
        for (int ct = 0; ct < 4; ct++) {
          float v = acc[rt][ct][reg] + bv[ct];
          outf[(size_t)r * 256 + colbase + ct * 16] = v;
          outb[(size_t)r * 256 + colbase + ct * 16] = f2bf(v);
        }
      }
    }
}

// ---------------- fused GIN layer (+ optional attention logits, single-pass) ----------------
// GEMM1+LN+ReLU -> T1(LDS) -> GEMM2+LN+ReLU+resid -> h/hb [-> T1 -> att logits if ATT]
// GEMM1/GEMM2 use the counted-vmcnt double-buffered gload_lds pipeline.
// ATT: single pass, wave==head, acc[4][8], B staged into the 32KB Bs union (512x32 chunk).
// T1 swizzle: row r, 16B-slot s stored at phys slot s^(r&31).
template <bool WF, bool ATT>
__global__ __launch_bounds__(256) void k_gin(
    const unsigned short* __restrict__ Ab,
    const unsigned short* __restrict__ B1t, const float* __restrict__ bias1,
    const float* __restrict__ g1v, const float* __restrict__ be1,
    const unsigned short* __restrict__ B2t, const float* __restrict__ bias2,
    const float* __restrict__ g2v, const float* __restrict__ be2,
    const float* __restrict__ resid, float* __restrict__ outf,
    unsigned short* __restrict__ outb,
    const unsigned short* __restrict__ aW1T, const float* __restrict__ ab1,
    const float* __restrict__ aW2v, const float* __restrict__ ab2,
    float* __restrict__ logitsT) {
  __shared__ unsigned short As[2][64 * 32];   // 2 x 4 KB
  __shared__ unsigned short Bs[2][256 * 32];  // 2 x 16 KB (union = 512x32 for ATT)
  __shared__ unsigned short T1[64 * 256];     // 32 KB, slot-swizzled
  __shared__ float redS[4][64];
  __shared__ float redQ[4][64];
  __shared__ float mvM[64], mvI[64];
  int t = threadIdx.x, lane = t & 63, wave = t >> 6;
  int row0 = blockIdx.x * 64;
  int m16 = lane & 15, kq = lane >> 4;
  int colbase = wave * 64 + m16;
  int arow = t >> 2, a2 = t & 3;
  int asl = a2 ^ (arow & 3);
  int agr = row0 + arow; if (agr >= NN) agr = NN - 1;
  const unsigned short* Ag = Ab + (size_t)agr * 256 + asl * 8;
  int brow_[4], bsl_[4];
#pragma unroll
  for (int j = 0; j < 4; j++) {
    int s = j * 256 + t;
    brow_[j] = s >> 2;
    bsl_[j] = (s & 3) ^ (brow_[j] & 3);
  }
  auto stage1 = [&](int c, int p) {  // 5 loads: A chunk + B1 chunk
    int k0 = c * 32;
    ldsload16(Ag + k0, &As[p][wave * 512]);
#pragma unroll
    for (int j = 0; j < 4; j++)
      ldsload16(&B1t[(size_t)brow_[j] * 256 + k0 + bsl_[j] * 8],
                &Bs[p][(j * 256 + wave * 64) * 8]);
  };
  auto stageB = [&](const unsigned short* Bp_, int c, int p) {  // 4 loads: B chunk only
    int k0 = c * 32;
#pragma unroll
    for (int j = 0; j < 4; j++)
      ldsload16(&Bp_[(size_t)brow_[j] * 256 + k0 + bsl_[j] * 8],
                &Bs[p][(j * 256 + wave * 64) * 8]);
  };

  f32x4 acc[4][4];
#pragma unroll
  for (int i = 0; i < 4; i++)
#pragma unroll
    for (int j = 0; j < 4; j++) acc[i][j] = (f32x4)(0.f);

  // ---------------- GEMM1 K-loop ----------------
  stage1(0, 0);
  stage1(1, 1);
#pragma unroll
  for (int c = 0; c < 8; c++) {
    if (c < 7) asm volatile("s_waitcnt vmcnt(5)" ::: "memory");
    else       asm volatile("s_waitcnt vmcnt(0)" ::: "memory");
    __builtin_amdgcn_s_barrier();
    asm volatile("" ::: "memory");
    const unsigned short* Ap = As[c & 1];
    const unsigned short* Bp = Bs[c & 1];
    short8 a[4], b[4];
#pragma unroll
    for (int rt = 0; rt < 4; rt++) {
      int row = rt * 16 + m16;
      a[rt] = *(const short8*)&Ap[row * 32 + ((kq ^ (row & 3)) * 8)];
    }
#pragma unroll
    for (int ct = 0; ct < 4; ct++) {
      int row = wave * 64 + ct * 16 + m16;
      b[ct] = *(const short8*)&Bp[row * 32 + ((kq ^ (row & 3)) * 8)];
    }
#pragma unroll
    for (int rt = 0; rt < 4; rt++)
#pragma unroll
      for (int ct = 0; ct < 4; ct++)
        acc[rt][ct] = __builtin_amdgcn_mfma_f32_16x16x32_bf16(a[rt], b[ct], acc[rt][ct], 0, 0, 0);
    asm volatile("" ::: "memory");
    __builtin_amdgcn_s_barrier();
    asm volatile("" ::: "memory");
    if (c + 2 < 8) stage1(c + 2, c & 1);
  }

  // ---------------- epilogue 1: bias + LN + ReLU -> T1 (swizzled) ----------------
  {
    float bv[4];
#pragma unroll
    for (int ct = 0; ct < 4; ct++) bv[ct] = bias1[colbase + ct * 16];
    float s[4][4], q[4][4];
#pragma unroll
    for (int rt = 0; rt < 4; rt++)
#pragma unroll
      for (int reg = 0; reg < 4; reg++) { s[rt][reg] = 0.f; q[rt][reg] = 0.f; }
#pragma unroll
    for (int rt = 0; rt < 4; rt++)
#pragma unroll
      for (int ct = 0; ct < 4; ct++)
#pragma unroll
        for (int reg = 0; reg < 4; reg++) {
          float v = acc[rt][ct][reg] + bv[ct];
          acc[rt][ct][reg] = v;
          s[rt][reg] += v;
          q[rt][reg] += v * v;
        }
#pragma unroll
    for (int off = 1; off < 16; off <<= 1) {
#pragma unroll
      for (int rt = 0; rt < 4; rt++)
#pragma unroll
        for (int reg = 0; reg < 4; reg++) {
          s[rt][reg] += __shfl_xor(s[rt][reg], off, 64);
          q[rt][reg] += __shfl_xor(q[rt][reg], off, 64);
        }
    }
    if (m16 == 0) {
#pragma unroll
      for (int rt = 0; rt < 4; rt++)
#pragma unroll
        for (int reg = 0; reg < 4; reg++) {
          redS[wave][rt * 16 + kq * 4 + reg] = s[rt][reg];
          redQ[wave][rt * 16 + kq * 4 + reg] = q[rt][reg];
        }
    }
    __syncthreads();
    if (t < 64) {
      float ss = redS[0][t] + redS[1][t] + redS[2][t] + redS[3][t];
      float qq = redQ[0][t] + redQ[1][t] + redQ[2][t] + redQ[3][t];
      float mean = ss * (1.f / 256.f);
      float var = qq * (1.f / 256.f) - mean * mean;
      mvM[t] = mean;
      mvI[t] = rsqrtf(var + 1e-5f);
    }
    __syncthreads();
    float gv[4], bev[4];
#pragma unroll
    for (int ct = 0; ct < 4; ct++) { gv[ct] = g1v[colbase + ct * 16]; bev[ct] = be1[colbase + ct * 16]; }
#pragma unroll
    for (int rt = 0; rt < 4; rt++)
#pragma unroll
      for (int reg = 0; reg < 4; reg++) {
        int rr = rt * 16 + kq * 4 + reg;
        float mean = mvM[rr], inv = mvI[rr];
#pragma unroll
        for (int ct = 0; ct < 4; ct++) {
          int col = colbase + ct * 16;
          float val = fmaxf((acc[rt][ct][reg] - mean) * inv * gv[ct] + bev[ct], 0.f);
          T1[rr * 256 + (((col >> 3) ^ (rr & 31)) * 8) + (col & 7)] = f2bf(val);
        }
      }
    __syncthreads();
  }

  // ---------------- GEMM2 K-loop (A from T1, B2 pipelined) ----------------
#pragma unroll
  for (int i = 0; i < 4; i++)
#pragma unroll
    for (int j = 0; j < 4; j++) acc[i][j] = (f32x4)(0.f);
  stageB(B2t, 0, 0);
  stageB(B2t, 1, 1);
#pragma unroll
  for (int c = 0; c < 8; c++) {
    if (c < 7) asm volatile("s_waitcnt vmcnt(4)" ::: "memory");
    else       asm volatile("s_waitcnt vmcnt(0)" ::: "memory");
    __builtin_amdgcn_s_barrier();
    asm volatile("" ::: "memory");
    const unsigned short* Bp = Bs[c & 1];
    short8 a[4], b[4];
#pragma unroll
    for (int rt = 0; rt < 4; rt++) {
      int row = rt * 16 + m16;
      int sl = (c * 4 + kq) ^ (row & 31);
      a[rt] = *(const short8*)&T1[row * 256 + sl * 8];
    }
#pragma unroll
    for (int ct = 0; ct < 4; ct++) {
      int row = wave * 64 + ct * 16 + m16;
      b[ct] = *(const short8*)&Bp[row * 32 + ((kq ^ (row & 3)) * 8)];
    }
#pragma unroll
    for (int rt = 0; rt < 4; rt++)
#pragma unroll
      for (int ct = 0; ct < 4; ct++)
        acc[rt][ct] = __builtin_amdgcn_mfma_f32_16x16x32_bf16(a[rt], b[ct], acc[rt][ct], 0, 0, 0);
    asm volatile("" ::: "memory");
    __builtin_amdgcn_s_barrier();
    asm volatile("" ::: "memory");
    if (c + 2 < 8) stageB(B2t, c + 2, c & 1);
  }

  // ---------------- epilogue 2: bias + LN + ReLU + resid -> outf/outb (+T1 if ATT) ----------------
  {
    float bv[4];
#pragma unroll
    for (int ct = 0; ct < 4; ct++) bv[ct] = bias2[colbase + ct * 16];
    float s[4][4], q[4][4];
#pragma unroll
    for (int rt = 0; rt < 4; rt++)
#pragma unroll
      for (int reg = 0; reg < 4; reg++) { s[rt][reg] = 0.f; q[rt][reg] = 0.f; }
#pragma unroll
    for (int rt = 0; rt < 4; rt++)
#pragma unroll
      for (int ct = 0; ct < 4; ct++)
#pragma unroll
        for (int reg = 0; reg < 4; reg++) {
          float v = acc[rt][ct][reg] + bv[ct];
          acc[rt][ct][reg] = v;
          s[rt][reg] += v;
          q[rt][reg] += v * v;
        }
#pragma unroll
    for (int off = 1; off < 16; off <<= 1) {
#pragma unroll
      for (int rt = 0; rt < 4; rt++)
#pragma unroll
        for (int reg = 0; reg < 4; reg++) {
          s[rt][reg] += __shfl_xor(s[rt][reg], off, 64);
          q[rt][reg] += __shfl_xor(q[rt][reg], off, 64);
        }
    }
    if (m16 == 0) {
#pragma unroll
      for (int rt = 0; rt < 4; rt++)
#pragma unroll
        for (int reg = 0; reg < 4; reg++) {
          redS[wave][rt * 16 + kq * 4 + reg] = s[rt][reg];
          redQ[wave][rt * 16 + kq * 4 + reg] = q[rt][reg];
        }
    }
    __syncthreads();
    if (t < 64) {
      float ss = redS[0][t] + redS[1][t] + redS[2][t] + redS[3][t];
      float qq = redQ[0][t] + redQ[1][t] + redQ[2][t] + redQ[3][t];
      float mean = ss * (1.f / 256.f);
      float var = qq * (1.f / 256.f) - mean * mean;
      mvM[t] = mean;
      mvI[t] = rsqrtf(var + 1e-5f);
    }
    __syncthreads();
    float gv[4], bev[4];
#pragma unroll
    for (int ct = 0; ct < 4; ct++) { gv[ct] = g2v[colbase + ct * 16]; bev[ct] = be2[colbase + ct * 16]; }
#pragma unroll
    for (int rt = 0; rt < 4; rt++)
#pragma unroll
      for (int reg = 0; reg < 4; reg++) {
        int rr = rt * 16 + kq * 4 + reg;
        int r = row0 + rr;
        if (r >= NN) continue;
        float mean = mvM[rr], inv = mvI[rr];
#pragma unroll
        for (int ct = 0; ct < 4; ct++) {
          int col = colbase + ct * 16;
          float val = fmaxf((acc[rt][ct][reg] - mean) * inv * gv[ct] + bev[ct], 0.f);
          val += resid[(size_t)r * 256 + col];
          if (WF) outf[(size_t)r * 256 + col] = val;
          outb[(size_t)r * 256 + col] = f2bf(val);
          if (ATT) T1[rr * 256 + (((col >> 3) ^ (rr & 31)) * 8) + (col & 7)] = f2bf(val);
        }
      }
  }

  // ---------------- attention logits: single pass, wave==head (R5 k_att layout) ----------------
  if (ATT) {
    __syncthreads();  // T1 writes visible; Bs free (GEMM2 done)
    f32x4 acc8[4][8];
#pragma unroll
    for (int i = 0; i < 4; i++)
#pragma unroll
      for (int j = 0; j < 8; j++) acc8[i][j] = (f32x4)(0.f);
    unsigned short* BsU = &Bs[0][0];  // 512 rows x 32 k union
    int brow8_[8], bsl8_[8];
#pragma unroll
    for (int j = 0; j < 8; j++) {
      int s = j * 256 + t;
      brow8_[j] = s >> 2;
      bsl8_[j] = (s & 3) ^ (brow8_[j] & 3);
    }
#pragma unroll
    for (int c = 0; c < 8; c++) {
#pragma unroll
      for (int j = 0; j < 8; j++)
        ldsload16(&aW1T[(size_t)brow8_[j] * 256 + c * 32 + bsl8_[j] * 8],
                  &BsU[(j * 256 + wave * 64) * 8]);
      __syncthreads();
      short8 a[4];
#pragma unroll
      for (int rt = 0; rt < 4; rt++) {
        int row = rt * 16 + m16;
        int sl = (c * 4 + kq) ^ (row & 31);
        a[rt] = *(const short8*)&T1[row * 256 + sl * 8];
      }
#pragma unroll
      for (int ct = 0; ct < 8; ct++) {
        int row = wave * 128 + ct * 16 + m16;
        short8 b = *(const short8*)&BsU[row * 32 + ((kq ^ (row & 3)) * 8)];
#pragma unroll
        for (int rt = 0; rt < 4; rt++)
          acc8[rt][ct] = __builtin_amdgcn_mfma_f32_16x16x32_bf16(a[rt], b, acc8[rt][ct], 0, 0, 0);
      }
      __syncthreads();
    }
    const float* b1k = ab1 + wave * 128;
    const float* w2k = aW2v + wave * 128;
    float p[4][4];
#pragma unroll
    for (int rt = 0; rt < 4; rt++)
#pragma unroll
      for (int reg = 0; reg < 4; reg++) p[rt][reg] = 0.f;
#pragma unroll
    for (int ct = 0; ct < 8; ct++) {
      int col = ct * 16 + m16;
      float b1v = b1k[col], w2v = w2k[col];
#pragma unroll
      for (int rt = 0; rt < 4; rt++)
#pragma unroll
        for (int reg = 0; reg < 4; reg++) {
          float xv = acc8[rt][ct][reg] + b1v;
          xv = fminf(fmaxf(xv, -10.f), 10.f);
          float ex = __expf(2.f * xv);
          p[rt][reg] += (ex - 1.f) / (ex + 1.f) * w2v;
        }
    }
#pragma unroll
    for (int off = 1; off < 16; off <<= 1)
#pragma unroll
      for (int rt = 0; rt < 4; rt++)
#pragma unroll
        for (int reg = 0; reg < 4; reg++) p[rt][reg] += __shfl_xor(p[rt][reg], off, 64);
    if (m16 == 0) {
      float b2v = ab2[wave];
#pragma unroll
      for (int rt = 0; rt < 4; rt++)
#pragma unroll
        for (int reg = 0; reg < 4; reg++) {
          int r = row0 + rt * 16 + kq * 4 + reg;
          if (r < NN) logitsT[(size_t)wave * NN + r] = p[rt][reg] + b2v;
        }
    }
  }
}

// ---------------- softmax over N per head ----------------
__global__ void k_smax1(const float* __restrict__ logitsT, float* __restrict__ pmax,
                        float* __restrict__ psum) {
  int k = blockIdx.y;
  int tid = threadIdx.x;
  const float* L = logitsT + (size_t)k * NN;
  __shared__ float sm[256];
  float mx = -1e30f;
  for (int i = blockIdx.x * 256 + tid; i < NN; i += 128 * 256) mx = fmaxf(mx, L[i]);
  sm[tid] = mx; __syncthreads();
  for (int o = 128; o >= 1; o >>= 1) { if (tid < o) sm[tid] = fmaxf(sm[tid], sm[tid + o]); __syncthreads(); }
  float bmax = sm[0];
  __syncthreads();
  float s = 0.f;
  for (int i = blockIdx.x * 256 + tid; i < NN; i += 128 * 256) s += __expf(L[i] - bmax);
  sm[tid] = s; __syncthreads();
  for (int o = 128; o >= 1; o >>= 1) { if (tid < o) sm[tid] += sm[tid + o]; __syncthreads(); }
  if (tid == 0) { pmax[k * 128 + blockIdx.x] = bmax; psum[k * 128 + blockIdx.x] = sm[0]; }
}

__global__ void k_smax2(const float* __restrict__ pmax, const float* __restrict__ psum,
                        float* __restrict__ gs) {
  int k = blockIdx.x;
  int tid = threadIdx.x;  // 128
  __shared__ float sm[128], sv[128];
  float m = pmax[k * 128 + tid];
  sm[tid] = m; __syncthreads();
  for (int o = 64; o >= 1; o >>= 1) { if (tid < o) sm[tid] = fmaxf(sm[tid], sm[tid + o]); __syncthreads(); }
  float gm = sm[0];
  __syncthreads();
  sv[tid] = psum[k * 128 + tid] * __expf(m - gm);
  __syncthreads();
  for (int o = 64; o >= 1; o >>= 1) { if (tid < o) sv[tid] += sv[tid + o]; __syncthreads(); }
  if (tid == 0) { gs[k * 2] = gm; gs[k * 2 + 1] = sv[0]; }
}

// ------------- a = softmax, attn output, z[k][d] partials -------------
__global__ void k_attnz(const float* __restrict__ logitsT, const float* __restrict__ gs,
                        const unsigned short* __restrict__ hb, float* __restrict__ out_attn,
                        float* __restrict__ z) {
  int n0 = blockIdx.x * 128;
  int tid = threadIdx.x;
  __shared__ float a[4][128];
  for (int i = tid; i < 512; i += 256) {
    int k = i >> 7, n = i & 127;
    float v = 0.f;
    if (n0 + n < NN) v = __expf(logitsT[(size_t)k * NN + n0 + n] - gs[k * 2]) / gs[k * 2 + 1];
    a[k][n] = v;
  }
  __syncthreads();
  for (int i = tid; i < 512; i += 256) {
    int n = i >> 2, k = i & 3;
    if (n0 + n < NN) out_attn[(size_t)(n0 + n) * 4 + k] = a[k][n];
  }
  float z0 = 0.f, z1 = 0.f, z2 = 0.f, z3 = 0.f;
  int d = tid;  // 256 dims
  int nmax = NN - n0; if (nmax > 128) nmax = 128;
  for (int n = 0; n < nmax; n++) {
    float hv = bf2f(hb[(size_t)(n0 + n) * 256 + d]);
    z0 += a[0][n] * hv; z1 += a[1][n] * hv; z2 += a[2][n] * hv; z3 += a[3][n] * hv;
  }
  atomicAdd(&z[0 * 256 + d], z0);
  atomicAdd(&z[1 * 256 + d], z1);
  atomicAdd(&z[2 * 256 + d], z2);
  atomicAdd(&z[3 * 256 + d], z3);
}

// ---------------- tiny classifier ----------------
__global__ void k_cls(const float* __restrict__ z, const float* __restrict__ Wc1,
                      const float* __restrict__ bc1, const float* __restrict__ g1,
                      const float* __restrict__ b1, const float* __restrict__ Wc2,
                      const float* __restrict__ bc2, const float* __restrict__ g2,
                      const float* __restrict__ b2, const float* __restrict__ Wc3,
                      const float* __restrict__ bc3, float* __restrict__ out) {
  int tid = threadIdx.x;  // 256
  __shared__ float za[256];
  __shared__ float buf[256];
  __shared__ float c1s[128];
  __shared__ float c2s[64];
  za[tid] = 0.25f * (z[tid] + z[256 + tid] + z[512 + tid] + z[768 + tid]);
  __syncthreads();
  float v1 = 0.f;
  if (tid < 128) {
    for (int d = 0; d < 256; d++) v1 += za[d] * Wc1[d * 128 + tid];
    v1 += bc1[tid];
  }
  buf[tid] = (tid < 128) ? v1 : 0.f; __syncthreads();
  for (int o = 128; o >= 1; o >>= 1) { if (tid < o) buf[tid] += buf[tid + o]; __syncthreads(); }
  float mean1 = buf[0] * (1.f / 128.f);
  __syncthreads();
  buf[tid] = (tid < 128) ? (v1 - mean1) * (v1 - mean1) : 0.f; __syncthreads();
  for (int o = 128; o >= 1; o >>= 1) { if (tid < o) buf[tid] += buf[tid + o]; __syncthreads(); }
  float inv1 = rsqrtf(buf[0] * (1.f / 128.f) + 1e-5f);
  __syncthreads();
  if (tid < 128) c1s[tid] = fmaxf((v1 - mean1) * inv1 * g1[tid] + b1[tid], 0.f);
  __syncthreads();
  float v2 = 0.f;
  if (tid < 64) {
    for (int d = 0; d < 128; d++) v2 += c1s[d] * Wc2[d * 64 + tid];
    v2 += bc2[tid];
  }
  buf[tid] = (tid < 64) ? v2 : 0.f; __syncthreads();
  for (int o = 128; o >= 1; o >>= 1) { if (tid < o) buf[tid] += buf[tid + o]; __syncthreads(); }
  float mean2 = buf[0] * (1.f / 64.f);
  __syncthreads();
  buf[tid] = (tid < 64) ? (v2 - mean2) * (v2 - mean2) : 0.f; __syncthreads();
  for (int o = 128; o >= 1; o >>= 1) { if (tid < o) buf[tid] += buf[tid + o]; __syncthreads(); }
  float inv2 = rsqrtf(buf[0] * (1.f / 64.f) + 1e-5f);
  __syncthreads();
  if (tid < 64) c2s[tid] = fmaxf((v2 - mean2) * inv2 * g2[tid] + b2[tid], 0.f);
  __syncthreads();
  if (tid < 7) {
    float l = 0.f;
    for (int d = 0; d < 64; d++) l += c2s[d] * Wc3[d * 7 + tid];
    buf[tid] = l + bc3[tid];
  }
  __syncthreads();
  if (tid == 0) {
    float mx = -1e30f;
    for (int i = 0; i < 7; i++) mx = fmaxf(mx, buf[i]);
    float s = 0.f;
    for (int i = 0; i < 7; i++) s += __expf(buf[i] - mx);
    for (int i = 0; i < 7; i++) out[i] = __expf(buf[i] - mx) / s;
  }
}

extern "C" void kernel_launch(void* const* d_in, const int* in_sizes, int n_in,
                              void* d_out, int out_size, void* d_ws, size_t ws_size,
                              hipStream_t stream) {
  const float* x       = (const float*)d_in[0];
  const int*   ei      = (const int*)d_in[1];
  const float* W_in    = (const float*)d_in[2];
  const float* b_in    = (const float*)d_in[3];
  const float* gin_W1  = (const float*)d_in[4];
  const float* gin_b1  = (const float*)d_in[5];
  const float* gin_lng = (const float*)d_in[6];
  const float* gin_lnb = (const float*)d_in[7];
  const float* gin_W2  = (const float*)d_in[8];
  const float* gin_b2  = (const float*)d_in[9];
  const float* eps     = (const float*)d_in[10];
  const float* ln_g    = (const float*)d_in[11];
  const float* ln_b    = (const float*)d_in[12];
  const float* att_W1  = (const float*)d_in[13];
  const float* att_b1  = (const float*)d_in[14];
  const float* att_W2  = (const float*)d_in[15];
  const float* att_b2  = (const float*)d_in[16];
  const float* Wc1     = (const float*)d_in[17];
  const float* bc1     = (const float*)d_in[18];
  const float* lnc1_g  = (const float*)d_in[19];
  const float* lnc1_b  = (const float*)d_in[20];
  const float* Wc2     = (const float*)d_in[21];
  const float* bc2     = (const float*)d_in[22];
  const float* lnc2_g  = (const float*)d_in[23];
  const float* lnc2_b  = (const float*)d_in[24];
  const float* Wc3     = (const float*)d_in[25];
  const float* bc3     = (const float*)d_in[26];
  float* out = (float*)d_out;
  (void)in_sizes; (void)n_in; (void)out_size; (void)ws_size;

  char* wsb = (char*)d_ws;
  size_t off = 0;
  auto alloc = [&](size_t bytes) {
    char* p = wsb + off;
    off += (bytes + 255) & ~(size_t)255;
    return p;
  };
  float*          h       = (float*)alloc((size_t)NN * HH * 4);
  unsigned short* hb      = (unsigned short*)alloc((size_t)NN * HH * 2);
  unsigned short* mb1     = (unsigned short*)alloc((size_t)NN * HH * 2);
  unsigned short* WinT    = (unsigned short*)alloc((size_t)HH * FF * 2);
  unsigned short* g1T     = (unsigned short*)alloc((size_t)2 * HH * HH * 2);
  unsigned short* g2T     = (unsigned short*)alloc((size_t)2 * HH * HH * 2);
  unsigned short* aW1T    = (unsigned short*)alloc((size_t)4 * 128 * HH * 2);
  float*          logitsT = (float*)alloc((size_t)4 * NN * 4);
  int*            deg     = (int*)alloc((size_t)NN * 4);
  int*            rowptr  = (int*)alloc((size_t)(NN + 1) * 4);
  int*            cursor  = (int*)alloc((size_t)NN * 4);
  int*            csr_src = (int*)alloc((size_t)NE * 4);
  float*          pmax    = (float*)alloc(4 * 128 * 4);
  float*          psum    = (float*)alloc(4 * 128 * 4);
  float*          gs      = (float*)alloc(8 * 4);
  float*          z       = (float*)alloc(4 * 256 * 4);

  const int* srcv = ei;
  const int* dstv = ei + NE;

  // weight transposes + casts (tiny, batched over blockIdx.z)
  k_tcast<<<dim3((HH + 31) / 32, (FF + 31) / 32, 1), 256, 0, stream>>>(W_in, WinT, FF, HH);
  k_tcast<<<dim3(8, 8, 2), 256, 0, stream>>>(gin_W1, g1T, HH, HH);
  k_tcast<<<dim3(8, 8, 2), 256, 0, stream>>>(gin_W2, g2T, HH, HH);
  k_tcast<<<dim3(4, 8, 4), 256, 0, stream>>>(att_W1, aW1T, HH, 128);

  // CSR build
  hipMemsetAsync(deg, 0, (size_t)NN * 4, stream);
  hipMemsetAsync(z, 0, 4 * 256 * 4, stream);
  k_count<<<(NE + 255) / 256, 256, 0, stream>>>(dstv, deg);
  k_scan<<<1, 1024, 0, stream>>>(deg, rowptr);
  hipMemcpyAsync(cursor, rowptr, (size_t)NN * 4, hipMemcpyDeviceToDevice, stream);
  k_scatter<<<(NE + 255) / 256, 256, 0, stream>>>(srcv, dstv, cursor, csr_src);

  int gblocks = (NN + 63) / 64;  // 782
  // h = x @ W_in + b_in  (fp32 A cast to bf16 in staging); also emit hb
  k_mmff<<<gblocks, 256, 0, stream>>>(x, WinT, b_in, h, hb);

  for (int l = 0; l < 2; l++) {
    k_agg<<<(NN + 3) / 4, 256, 0, stream>>>(hb, rowptr, csr_src, eps, l, mb1);
    // fused GIN layer: GEMM1+LN+ReLU -> (LDS) -> GEMM2+LN+ReLU+resid -> h/hb [+att logits]
    if (l == 0)
      k_gin<true, false><<<gblocks, 256, 0, stream>>>(
          mb1, g1T + (size_t)l * HH * HH, gin_b1 + l * HH, gin_lng + l * HH, gin_lnb + l * HH,
          g2T + (size_t)l * HH * HH, gin_b2 + l * HH, ln_g + l * HH, ln_b + l * HH,
          h, h, hb, nullptr, nullptr, nullptr, nullptr, nullptr);
    else
      k_gin<false, true><<<gblocks, 256, 0, stream>>>(
          mb1, g1T + (size_t)l * HH * HH, gin_b1 + l * HH, gin_lng + l * HH, gin_lnb + l * HH,
          g2T + (size_t)l * HH * HH, gin_b2 + l * HH, ln_g + l * HH, ln_b + l * HH,
          h, nullptr, hb, aW1T, att_b1, att_W2, att_b2, logitsT);
  }

  k_smax1<<<dim3(128, 4), 256, 0, stream>>>(logitsT, pmax, psum);
  k_smax2<<<4, 128, 0, stream>>>(pmax, psum, gs);
  k_attnz<<<(NN + 127) / 128, 256, 0, stream>>>(logitsT, gs, hb, out + 7, z);
  k_cls<<<1, 256, 0, stream>>>(z, Wc1, bc1, lnc1_g, lnc1_b, Wc2, bc2, lnc2_g, lnc2_b,
                               Wc3, bc3, out);
}